// Round 5
// baseline (66.238 us; speedup 1.0000x reference)
//
#include <hip/hip_runtime.h>
#include <hip/hip_bf16.h>

typedef __attribute__((ext_vector_type(8))) short short8;
typedef __attribute__((ext_vector_type(16))) float f32x16;

constexpr int N_PAIRS = 4096;
constexpr int TWO_N = 8192;
constexpr int D = 256;
constexpr float E2 = 7.3890560989306495f;        // exp(1/temp), temp=0.5
// sqrt(2 * log2(e)): GEMM of prescaled operands yields 2*log2e*sim, so
// denom term = exp2(c) = single v_exp_f32.
constexpr float PRESCALE = 1.6986435527128123f;

__device__ inline float wave_reduce_sum(float v) {
#pragma unroll
  for (int m = 32; m; m >>= 1) v += __shfl_xor(v, m, 64);
  return v;
}

__device__ inline unsigned short f2bf(float x) {
  __hip_bfloat16 h = __float2bfloat16(x);
  return __builtin_bit_cast(unsigned short, h);
}

// k1: normalize rows of z=[zi;zj] -> bf16 zn (pre-scaled by PRESCALE),
//     and compute positive-pair sims in fp32 (exact cosine, unscaled).
__global__ void k_norm_pos(const float* __restrict__ zi, const float* __restrict__ zj,
                           unsigned short* __restrict__ zn, float* __restrict__ simpos) {
  __shared__ float s_inv[4];
  int tid = threadIdx.x;
  int w = tid >> 6, l = tid & 63;
  int p = blockIdx.x * 2 + (w >> 1);   // pair index 0..4095
  int half = w & 1;                    // 0 -> zi row, 1 -> zj row
  const float* src = half ? (zj + (size_t)p * D) : (zi + (size_t)p * D);
  float4 v = reinterpret_cast<const float4*>(src)[l];
  float ss = v.x * v.x + v.y * v.y + v.z * v.z + v.w * v.w;
  ss = wave_reduce_sum(ss);
  float nrm = sqrtf(ss);
  float inv = 1.0f / fmaxf(nrm, 1e-8f);
  if (l == 0) s_inv[w] = inv;
  float sc = inv * PRESCALE;
  int row = p + half * N_PAIRS;
  ushort4 o;
  o.x = f2bf(v.x * sc);
  o.y = f2bf(v.y * sc);
  o.z = f2bf(v.z * sc);
  o.w = f2bf(v.w * sc);
  reinterpret_cast<ushort4*>(zn + (size_t)row * D)[l] = o;
  __syncthreads();
  if (half == 0) {  // waves 0 and 2 compute the fp32 positive-pair sims
    const float4* a = reinterpret_cast<const float4*>(zi + (size_t)p * D);
    const float4* b = reinterpret_cast<const float4*>(zj + (size_t)p * D);
    float4 x = a[l], y = b[l];
    float d = x.x * y.x + x.y * y.y + x.z * y.z + x.w * y.w;
    d = wave_reduce_sum(d);
    if (l == 0) simpos[p] = d * s_inv[w] * s_inv[w + 1];
  }
}

// k2: per row r accumulate sum_j exp2(c[r][j]) via bf16 MFMA.
// 512 blocks (64 rowblk x 8 col-splits) x 256 thr (4 waves: 2 rgrp x 2 cgrp).
// 2 blocks/CU (2x32KB LDS). REG-STAGING (m151/HK): global->reg with
// CONTIGUOUS lane addressing (coalesced 1KB/instr), then ds_write_b128 to
// the XOR-swizzled LDS address (permutation within 512B row: conflict-free).
// T14 split: loads issued at chunk top, ds_write after MFMA phases.
__global__ __launch_bounds__(256, 2)
void k_simsum(const unsigned short* __restrict__ zn, float* __restrict__ partial) {
  __shared__ short lds[2][64 * 256];   // 2 x 32 KB
  const short* znS = reinterpret_cast<const short*>(zn);
  int tid = threadIdx.x;
  int w = tid >> 6, l = tid & 63;
  int lo = l & 31, hi = l >> 5;
  int rgrp = w >> 1, cgrp = w & 1;
  int rowblk = blockIdx.x >> 3, split = blockIdx.x & 7;
  int arowbase = rowblk * 128 + rgrp * 64;
  int colbase = split * 1024;
  int lrow = l >> 5, lslot = l & 31;

  // A fragments resident: 2 strips x 16 k-frags (lane: row=lo, k=hi*8+..)
  short8 a0[16], a1[16];
  {
    const short* r0 = znS + (size_t)(arowbase + lo) * D + hi * 8;
    const short* r1 = znS + (size_t)(arowbase + 32 + lo) * D + hi * 8;
#pragma unroll
    for (int kf = 0; kf < 16; ++kf) {
      a0[kf] = *reinterpret_cast<const short8*>(r0 + kf * 16);
      a1[kf] = *reinterpret_cast<const short8*>(r1 + kf * 16);
    }
  }

  int r = cgrp * 32 + lo;              // B row (sim column) within 64-col chunk
  int rx = lo;                         // r & 31 == lo for both cgrps
  f32x16 rs0 = (f32x16)0.0f, rs1 = (f32x16)0.0f;

  // prologue: stage chunk 0 (coalesced load -> swizzled ds_write)
  {
    short8 st[8];
#pragma unroll
    for (int i = 0; i < 8; ++i) {
      int row = w * 16 + 2 * i + lrow;
      st[i] = *reinterpret_cast<const short8*>(znS + (size_t)(colbase + row) * D + lslot * 8);
    }
#pragma unroll
    for (int i = 0; i < 8; ++i) {
      int row = w * 16 + 2 * i + lrow;
      *reinterpret_cast<short8*>(&lds[0][row * 256 + (lslot ^ (row & 31)) * 8]) = st[i];
    }
  }
  __syncthreads();

  for (int ch = 0; ch < 16; ++ch) {
    // T14 issue-early: coalesced global loads for chunk ch+1 (latency hides
    // under this chunk's ds_read+MFMA phases)
    short8 st[8];
    int cbn = colbase + (ch + 1) * 64;
    if (ch < 15) {
#pragma unroll
      for (int i = 0; i < 8; ++i) {
        int row = w * 16 + 2 * i + lrow;
        st[i] = *reinterpret_cast<const short8*>(znS + (size_t)(cbn + row) * D + lslot * 8);
      }
    }

    const short* lrp = &lds[ch & 1][r * 256];
    f32x16 c0 = (f32x16)0.0f, c1 = (f32x16)0.0f;
#pragma unroll
    for (int p = 0; p < 4; ++p) {
      short8 b[4];
#pragma unroll
      for (int s = 0; s < 4; ++s)
        b[s] = *reinterpret_cast<const short8*>(lrp + (((p * 4 + s) * 2 + hi) ^ rx) * 8);
      __builtin_amdgcn_s_setprio(1);
#pragma unroll
      for (int s = 0; s < 4; ++s) {
        c0 = __builtin_amdgcn_mfma_f32_32x32x16_bf16(a0[p * 4 + s], b[s], c0, 0, 0, 0);
        c1 = __builtin_amdgcn_mfma_f32_32x32x16_bf16(a1[p * 4 + s], b[s], c1, 0, 0, 0);
      }
      __builtin_amdgcn_s_setprio(0);
    }

    // T14 write-late: publish chunk ch+1 into the other buffer
    if (ch < 15) {
      short* dbuf = &lds[(ch + 1) & 1][0];
#pragma unroll
      for (int i = 0; i < 8; ++i) {
        int row = w * 16 + 2 * i + lrow;
        *reinterpret_cast<short8*>(&dbuf[row * 256 + (lslot ^ (row & 31)) * 8]) = st[i];
      }
    }

    // operands pre-scaled by sqrt(2*log2e) -> c = 2*log2e*sim; exp2 is 1 instr
#pragma unroll
    for (int q = 0; q < 16; ++q) {
      rs0[q] += __builtin_amdgcn_exp2f(c0[q]);
      rs1[q] += __builtin_amdgcn_exp2f(c1[q]);
    }
    __syncthreads();   // publishes ds_writes for next chunk
  }

  // reduce across the 32 columns (lane dimension) of each half-wave
#pragma unroll
  for (int m = 1; m < 32; m <<= 1) {
#pragma unroll
    for (int q = 0; q < 16; ++q) {
      rs0[q] += __shfl_xor(rs0[q], m, 64);
      rs1[q] += __shfl_xor(rs1[q], m, 64);
    }
  }
  if (lo == 0) {
    int pc = split * 2 + cgrp;  // 16 partials per row (8 splits x 2 cgrp)
#pragma unroll
    for (int q = 0; q < 16; ++q) {
      int rf = (q & 3) + 8 * (q >> 2) + 4 * hi;  // m74/m101-verified C row map
      partial[(size_t)(arowbase + rf) * 16 + pc] = rs0[q];
      partial[(size_t)(arowbase + 32 + rf) * 16 + pc] = rs1[q];
    }
  }
}

// k3a: 64 blocks x 128 threads; thread = one row; per-block loss partial.
__global__ void k_final1(const float* __restrict__ partial, const float* __restrict__ simpos,
                         float* __restrict__ blocksum) {
  __shared__ float red[2];
  int tid = threadIdx.x;
  int r = blockIdx.x * 128 + tid;
  const float4* p = reinterpret_cast<const float4*>(partial + (size_t)r * 16);
  float4 q0 = p[0], q1 = p[1], q2 = p[2], q3 = p[3];
  float denom = ((q0.x + q0.y) + (q0.z + q0.w)) + ((q1.x + q1.y) + (q1.z + q1.w)) +
                ((q2.x + q2.y) + (q2.z + q2.w)) + ((q3.x + q3.y) + (q3.z + q3.w)) - E2;
  float acc = __logf(denom) - 2.0f * simpos[r & (N_PAIRS - 1)];
  acc = wave_reduce_sum(acc);
  int w = tid >> 6, l = tid & 63;
  if (l == 0) red[w] = acc;
  __syncthreads();
  if (tid == 0) blocksum[blockIdx.x] = red[0] + red[1];
}

// k3b: final reduce of 64 block sums.
__global__ void k_final2(const float* __restrict__ blocksum, float* __restrict__ out) {
  int l = threadIdx.x & 63;
  float v = blocksum[l];
  v = wave_reduce_sum(v);
  if (l == 0) out[0] = v * (1.0f / TWO_N);
}

extern "C" void kernel_launch(void* const* d_in, const int* in_sizes, int n_in,
                              void* d_out, int out_size, void* d_ws, size_t ws_size,
                              hipStream_t stream) {
  const float* zi = (const float*)d_in[0];
  const float* zj = (const float*)d_in[1];
  char* ws = (char*)d_ws;
  unsigned short* zn = (unsigned short*)ws;                       // 4 MB bf16 normalized (x PRESCALE)
  float* simpos = (float*)(ws + 4u * 1024u * 1024u);              // 16 KB
  float* partial = (float*)(ws + 4u * 1024u * 1024u + 65536u);    // 512 KB [8192][16]
  float* blocksum = (float*)(ws + 4u * 1024u * 1024u + 65536u + 524288u);  // 256 B
  float* out = (float*)d_out;

  k_norm_pos<<<2048, 256, 0, stream>>>(zi, zj, zn, simpos);
  k_simsum<<<512, 256, 0, stream>>>(zn, partial);
  k_final1<<<64, 128, 0, stream>>>(partial, simpos, blocksum);
  k_final2<<<1, 64, 0, stream>>>(blocksum, out);
}

// Round 6
// 55.005 us; speedup vs baseline: 1.2042x; 1.2042x over previous
//
#include <hip/hip_runtime.h>
#include <hip/hip_bf16.h>

typedef __attribute__((ext_vector_type(8))) short short8;
typedef __attribute__((ext_vector_type(16))) float f32x16;

constexpr int N_PAIRS = 4096;
constexpr int TWO_N = 8192;
constexpr int D = 256;
constexpr float E2 = 7.3890560989306495f;        // exp(1/temp), temp=0.5
// sqrt(2 * log2(e)): GEMM of prescaled operands yields 2*log2e*sim, so
// denom term = exp2(c) = single v_exp_f32.
constexpr float PRESCALE = 1.6986435527128123f;

__device__ inline float wave_reduce_sum(float v) {
#pragma unroll
  for (int m = 32; m; m >>= 1) v += __shfl_xor(v, m, 64);
  return v;
}

__device__ inline unsigned short f2bf(float x) {
  __hip_bfloat16 h = __float2bfloat16(x);
  return __builtin_bit_cast(unsigned short, h);
}

// k1: normalize rows of z=[zi;zj] -> bf16 zn, PRE-SWIZZLED IN GLOBAL:
//     zn[row][slot] holds data slot^(row&31) of the row (16B slots).
//     So k2 can stage with fully-linear (coalesced) global_load_lds and
//     still get the bank-conflict-free XOR layout in LDS.
__global__ void k_norm_pos(const float* __restrict__ zi, const float* __restrict__ zj,
                           unsigned short* __restrict__ zn, float* __restrict__ simpos) {
  __shared__ float s_inv[4];
  int tid = threadIdx.x;
  int w = tid >> 6, l = tid & 63;
  int p = blockIdx.x * 2 + (w >> 1);   // pair index 0..4095
  int half = w & 1;                    // 0 -> zi row, 1 -> zj row
  const float* src = half ? (zj + (size_t)p * D) : (zi + (size_t)p * D);
  float4 v = reinterpret_cast<const float4*>(src)[l];
  float ss = v.x * v.x + v.y * v.y + v.z * v.z + v.w * v.w;
  ss = wave_reduce_sum(ss);
  float nrm = sqrtf(ss);
  float inv = 1.0f / fmaxf(nrm, 1e-8f);
  if (l == 0) s_inv[w] = inv;
  float sc = inv * PRESCALE;
  int row = p + half * N_PAIRS;
  ushort4 o;
  o.x = f2bf(v.x * sc);
  o.y = f2bf(v.y * sc);
  o.z = f2bf(v.z * sc);
  o.w = f2bf(v.w * sc);
  // lane l covers half-slot l (8B). 16B slot s = l>>1, half h = l&1.
  // swizzled position: (s ^ (row&31))*2 + h   (8B units within the row)
  int s = l >> 1, h = l & 1;
  int swz = ((s ^ (row & 31)) << 1) | h;
  reinterpret_cast<ushort4*>(zn + (size_t)row * D)[swz] = o;
  __syncthreads();
  if (half == 0) {  // waves 0 and 2 compute the fp32 positive-pair sims
    const float4* a = reinterpret_cast<const float4*>(zi + (size_t)p * D);
    const float4* b = reinterpret_cast<const float4*>(zj + (size_t)p * D);
    float4 x = a[l], y = b[l];
    float d = x.x * y.x + x.y * y.y + x.z * y.z + x.w * y.w;
    d = wave_reduce_sum(d);
    if (l == 0) simpos[p] = d * s_inv[w] * s_inv[w + 1];
  }
}

// k2: per row r accumulate sum_j exp2(c[r][j]) via bf16 MFMA.
// 512 blocks (64 rowblk x 8 col-splits) x 256 thr (4 waves: 2 rgrp x 2 cgrp),
// 2 blocks/CU. Staging: global_load_lds with LINEAR source+dest (zn is
// pre-swizzled in global), double-buffered 2x32KB. ds_read side uses the
// XOR addressing (conflict-free, counter-verified). A-fragment loads XOR
// their slot index to unswizzle.
__global__ __launch_bounds__(256, 2)
void k_simsum(const unsigned short* __restrict__ zn, float* __restrict__ partial) {
  __shared__ short lds[2][64 * 256];   // 2 x 32 KB
  const short* znS = reinterpret_cast<const short*>(zn);
  int tid = threadIdx.x;
  int w = tid >> 6, l = tid & 63;
  int lo = l & 31, hi = l >> 5;
  int rgrp = w >> 1, cgrp = w & 1;
  int rowblk = blockIdx.x >> 3, split = blockIdx.x & 7;
  int arowbase = rowblk * 128 + rgrp * 64;
  int colbase = split * 1024;
  int lrow = l >> 5, lslot = l & 31;

  // A fragments resident: 2 strips x 16 k-frags (lane: row=lo, k=hi*8+..).
  // zn is swizzled: slot s of row lives at s^(row&31); row&31 == lo here.
  short8 a0[16], a1[16];
  {
    const short* r0 = znS + (size_t)(arowbase + lo) * D;
    const short* r1 = znS + (size_t)(arowbase + 32 + lo) * D;
#pragma unroll
    for (int kf = 0; kf < 16; ++kf) {
      a0[kf] = *reinterpret_cast<const short8*>(r0 + (((kf * 2 + hi) ^ lo) * 8));
      a1[kf] = *reinterpret_cast<const short8*>(r1 + (((kf * 2 + hi) ^ lo) * 8));
    }
  }

  int r = cgrp * 32 + lo;              // B row (sim column) within 64-col chunk
  int rx = lo;                         // (chunk row) & 31 == lo for both cgrps
  f32x16 rs0 = (f32x16)0.0f, rs1 = (f32x16)0.0f;

  // stage 64 rows x 512B, linear: lane l <- row(w*16+2i+(l>>5)) bytes (l&31)*16
  auto stage = [&](short* buf, int cb) {
#pragma unroll
    for (int i = 0; i < 8; ++i) {
      int row = w * 16 + 2 * i + lrow;
      const short* gp = znS + (size_t)(cb + row) * D + lslot * 8;  // LINEAR
      short* lp = buf + (w * 16 + 2 * i) * 256;                    // uniform base
      __builtin_amdgcn_global_load_lds((const __attribute__((address_space(1))) void*)gp,
                                       (__attribute__((address_space(3))) void*)lp,
                                       16, 0, 0);
    }
  };

  stage(&lds[0][0], colbase);
  __syncthreads();

  for (int ch = 0; ch < 16; ++ch) {
    if (ch < 15) stage(&lds[(ch + 1) & 1][0], colbase + (ch + 1) * 64);
    const short* lrp = &lds[ch & 1][r * 256];
    f32x16 c0 = (f32x16)0.0f, c1 = (f32x16)0.0f;
#pragma unroll
    for (int p = 0; p < 4; ++p) {
      short8 b[4];
#pragma unroll
      for (int s = 0; s < 4; ++s)
        b[s] = *reinterpret_cast<const short8*>(lrp + (((p * 4 + s) * 2 + hi) ^ rx) * 8);
      __builtin_amdgcn_s_setprio(1);
#pragma unroll
      for (int s = 0; s < 4; ++s) {
        c0 = __builtin_amdgcn_mfma_f32_32x32x16_bf16(a0[p * 4 + s], b[s], c0, 0, 0, 0);
        c1 = __builtin_amdgcn_mfma_f32_32x32x16_bf16(a1[p * 4 + s], b[s], c1, 0, 0, 0);
      }
      __builtin_amdgcn_s_setprio(0);
    }
    // operands pre-scaled by sqrt(2*log2e) -> c = 2*log2e*sim; exp2 is 1 instr
#pragma unroll
    for (int q = 0; q < 16; ++q) {
      rs0[q] += __builtin_amdgcn_exp2f(c0[q]);
      rs1[q] += __builtin_amdgcn_exp2f(c1[q]);
    }
    __syncthreads();   // publishes next chunk's staged data (drains vmcnt)
  }

  // reduce across the 32 columns (lane dimension) of each half-wave
#pragma unroll
  for (int m = 1; m < 32; m <<= 1) {
#pragma unroll
    for (int q = 0; q < 16; ++q) {
      rs0[q] += __shfl_xor(rs0[q], m, 64);
      rs1[q] += __shfl_xor(rs1[q], m, 64);
    }
  }
  if (lo == 0) {
    int pc = split * 2 + cgrp;  // 16 partials per row (8 splits x 2 cgrp)
#pragma unroll
    for (int q = 0; q < 16; ++q) {
      int rf = (q & 3) + 8 * (q >> 2) + 4 * hi;  // m74/m101-verified C row map
      partial[(size_t)(arowbase + rf) * 16 + pc] = rs0[q];
      partial[(size_t)(arowbase + 32 + rf) * 16 + pc] = rs1[q];
    }
  }
}

// k3a: 64 blocks x 128 threads; thread = one row; per-block loss partial.
__global__ void k_final1(const float* __restrict__ partial, const float* __restrict__ simpos,
                         float* __restrict__ blocksum) {
  __shared__ float red[2];
  int tid = threadIdx.x;
  int r = blockIdx.x * 128 + tid;
  const float4* p = reinterpret_cast<const float4*>(partial + (size_t)r * 16);
  float4 q0 = p[0], q1 = p[1], q2 = p[2], q3 = p[3];
  float denom = ((q0.x + q0.y) + (q0.z + q0.w)) + ((q1.x + q1.y) + (q1.z + q1.w)) +
                ((q2.x + q2.y) + (q2.z + q2.w)) + ((q3.x + q3.y) + (q3.z + q3.w)) - E2;
  float acc = __logf(denom) - 2.0f * simpos[r & (N_PAIRS - 1)];
  acc = wave_reduce_sum(acc);
  int w = tid >> 6, l = tid & 63;
  if (l == 0) red[w] = acc;
  __syncthreads();
  if (tid == 0) blocksum[blockIdx.x] = red[0] + red[1];
}

// k3b: final reduce of 64 block sums.
__global__ void k_final2(const float* __restrict__ blocksum, float* __restrict__ out) {
  int l = threadIdx.x & 63;
  float v = blocksum[l];
  v = wave_reduce_sum(v);
  if (l == 0) out[0] = v * (1.0f / TWO_N);
}

extern "C" void kernel_launch(void* const* d_in, const int* in_sizes, int n_in,
                              void* d_out, int out_size, void* d_ws, size_t ws_size,
                              hipStream_t stream) {
  const float* zi = (const float*)d_in[0];
  const float* zj = (const float*)d_in[1];
  char* ws = (char*)d_ws;
  unsigned short* zn = (unsigned short*)ws;                       // 4 MB bf16 normalized, global-swizzled
  float* simpos = (float*)(ws + 4u * 1024u * 1024u);              // 16 KB
  float* partial = (float*)(ws + 4u * 1024u * 1024u + 65536u);    // 512 KB [8192][16]
  float* blocksum = (float*)(ws + 4u * 1024u * 1024u + 65536u + 524288u);  // 256 B
  float* out = (float*)d_out;

  k_norm_pos<<<2048, 256, 0, stream>>>(zi, zj, zn, simpos);
  k_simsum<<<512, 256, 0, stream>>>(zn, partial);
  k_final1<<<64, 128, 0, stream>>>(partial, simpos, blocksum);
  k_final2<<<1, 64, 0, stream>>>(blocksum, out);
}